// Round 11
// baseline (244.005 us; speedup 1.0000x reference)
//
#include <hip/hip_runtime.h>
#include <math.h>

#define BB 10
#define TT 12
#define FF 500
#define HH 200
#define G3 600
#define KP 224      // padded K for h (7*32)
#define NKS 7       // K-steps of 32
#define SLOTS 5     // j-tiles per wave (8 waves * 5 = 40); 4 in regs + 1 in LDS
#define RSLOTS 4
#define GHW 648     // ghf row stride in floats

// ws layout (float units):
#define WS_XW   0        // XW [120][600] fp32
#define WS_XWV  72000    // xw [120]
#define WS_FRAG 72128    // W_hh B-frags: 40 tiles * 7 ks * 64 lanes * 16B = 71680 dwords
#define WS_WHF  143808   // Wh hi/lo B-frags: 14 * 64 * 16B = 3584 dwords

typedef __attribute__((ext_vector_type(8))) short bf16x8;
typedef __attribute__((ext_vector_type(4))) float f32x4;

__device__ __forceinline__ unsigned short f2bf(float f) {
    unsigned int u = __float_as_uint(f);
    u = (u + 0x7fffu + ((u >> 16) & 1u)) >> 16;
    return (unsigned short)u;
}
__device__ __forceinline__ float bf2f(unsigned short h) {
    return __uint_as_float(((unsigned int)h) << 16);
}

// ---------------- K1: XW fp32, xw, W_hh B-frags (j = 40n + tile), Wh hi/lo frags ----
__global__ __launch_bounds__(256) void prep_kernel(
        const float* __restrict__ x, const float* __restrict__ wx,
        const float* __restrict__ W_ih, const float* __restrict__ W_hh,
        const float* __restrict__ Wh, float* __restrict__ ws) {
    int bl = blockIdx.x, tid = threadIdx.x;
    if (bl < 75) {
        __shared__ __align__(16) float wsm[8][FF];
        int j0 = bl * 8;
        for (int idx = tid; idx < 8 * FF; idx += 256)
            wsm[idx / FF][idx % FF] = W_ih[(j0 + idx / FF) * FF + (idx % FF)];
        __syncthreads();
        for (int p = tid; p < BB * TT * 8; p += 256) {
            int bt = p >> 3, jj = p & 7;
            const float4* xr = (const float4*)(x + bt * FF);
            const float4* wr = (const float4*)&wsm[jj][0];
            float acc = 0.f;
            for (int c = 0; c < FF / 4; ++c) {
                float4 a = xr[c], b = wr[c];
                acc += a.x * b.x + a.y * b.y + a.z * b.z + a.w * b.w;
            }
            ws[WS_XW + bt * G3 + j0 + jj] = acc;
        }
    } else if (bl < 91) {
        unsigned int* fr = (unsigned int*)(ws + WS_FRAG);
        int base = (bl - 75) * 4480;
        for (int q = tid; q < 4480; q += 256) {
            int d = base + q;
            int v = d & 3, lane = (d >> 2) & 63, pk = d >> 8;
            int ks = pk % NKS, tile = pk / NKS;
            int n = lane & 15;
            int k = ks * 32 + (lane >> 4) * 8 + 2 * v;
            unsigned int w = 0;
            if (k < HH && n < 15) {
                int j = 40 * n + tile;   // < 600
                w = (unsigned int)f2bf(W_hh[j * HH + k]) |
                    ((unsigned int)f2bf(W_hh[j * HH + k + 1]) << 16);
            }
            fr[d] = w;
        }
    } else if (bl < 99) {
        int dte = (bl - 91) * 15 + (tid >> 4), l = tid & 15;
        if (tid < 240) {
            float p = 0.f;
            for (int f = l; f < FF; f += 16) p += x[dte * FF + f] * wx[f];
            p += __shfl_xor(p, 8);
            p += __shfl_xor(p, 4);
            p += __shfl_xor(p, 2);
            p += __shfl_xor(p, 1);
            if (l == 0) ws[WS_XWV + dte] = p;
        }
    } else {
        unsigned int* fr = (unsigned int*)(ws + WS_WHF);
        for (int d = tid; d < 3584; d += 256) {
            int v = d & 3, lane = (d >> 2) & 63, pk = d >> 8;
            int qq = pk & 1, ks = pk >> 1;
            int t = lane & 15, k = ks * 32 + (lane >> 4) * 8 + 2 * v;
            unsigned int w = 0;
            if (t < TT && k < HH) {
                float f0 = Wh[t * HH + k], f1 = Wh[t * HH + k + 1];
                if (qq == 0) {
                    w = (unsigned int)f2bf(f0) | ((unsigned int)f2bf(f1) << 16);
                } else {
                    float l0 = f0 - bf2f(f2bf(f0)), l1 = f1 - bf2f(f2bf(f1));
                    w = (unsigned int)f2bf(l0) | ((unsigned int)f2bf(l1) << 16);
                }
            }
            fr[d] = w;
        }
    }
}

// hbf: bf16 h [16 rows(b)][KP], XOR-swizzled (ushort idx ^ (b&7)<<3)
__device__ __forceinline__ int hbf_idx(int r, int k) {
    return (r * KP + k) ^ ((r & 7) << 3);
}

// ---------------- K2: 12-step recurrence. MODE: 0=full, 1=noB1, 2=noB2mfma, 3=noSMreduce
// Ablation variants (MODE!=0) run BEFORE the full kernel and write deterministic
// dummy results to out; MODE=0 runs last and overwrites all of out.
template<int MODE>
__global__ __attribute__((amdgpu_waves_per_eu(2, 2))) __launch_bounds__(512)
void recurrence_kernel(
        const float* __restrict__ guidance, const float* __restrict__ bh,
        const float* __restrict__ b_ih, const float* __restrict__ b_hh,
        const float* __restrict__ h0, const float* __restrict__ ws,
        float* __restrict__ out) {
    const float* XW  = ws + WS_XW;
    const float* xww = ws + WS_XWV;

    __shared__ __align__(16) float ghf[16 * GHW];
    __shared__ __align__(16) unsigned short hbf[16 * KP];
    __shared__ __align__(16) bf16x8 wlds[8][NKS][64];
    __shared__ __align__(16) bf16x8 wh_lds[2][NKS][64];
    __shared__ __align__(16) float bsum_s[2 * HH];
    __shared__ __align__(16) float bihn_s[HH];
    __shared__ __align__(16) float bhhn_s[HH];
    __shared__ float guid_s[BB][TT], zr_s[BB][TT], xw_s[BB][TT];
    __shared__ float a_w[8][TT][12];
    __shared__ float bh_s[TT];

    int tid = threadIdx.x, wv = tid >> 6, lane = tid & 63;
    int ar = lane & 15, kg = lane >> 4;

    bf16x8 bfr[RSLOTS][NKS];
    {
        const bf16x8* fragp = (const bf16x8*)(ws + WS_FRAG);
        #pragma unroll
        for (int s = 0; s < RSLOTS; ++s)
            #pragma unroll
            for (int ks = 0; ks < NKS; ++ks)
                bfr[s][ks] = fragp[((SLOTS * wv + s) * NKS + ks) * 64 + lane];
        #pragma unroll
        for (int ks = 0; ks < NKS; ++ks)
            wlds[wv][ks][lane] = fragp[((SLOTS * wv + RSLOTS) * NKS + ks) * 64 + lane];
        const bf16x8* whp = (const bf16x8*)(ws + WS_WHF);
        for (int u = tid; u < 2 * NKS * 64; u += 512) {
            int l = u & 63, pk = u >> 6;
            wh_lds[pk & 1][pk >> 1][l] = whp[u];
        }
    }
    if (tid < BB * TT) {
        guid_s[tid / TT][tid % TT] = guidance[tid];
        xw_s[tid / TT][tid % TT]   = xww[tid];
    }
    for (int idx = tid; idx < 2 * HH; idx += 512) bsum_s[idx] = b_ih[idx] + b_hh[idx];
    for (int idx = tid; idx < HH; idx += 512) {
        bihn_s[idx] = b_ih[idx + 2 * HH];
        bhhn_s[idx] = b_hh[idx + 2 * HH];
    }
    if (tid < TT) bh_s[tid] = bh[tid];
    for (int idx = tid; idx < 16 * KP / 2; idx += 512) ((unsigned int*)hbf)[idx] = 0;
    float4 hq = (float4){0.f, 0.f, 0.f, 0.f};
    if (tid < 500) hq = *(const float4*)(h0 + (tid / 50) * HH + (tid % 50) * 4);
    __syncthreads();
    if (tid < 500) {
        int b = tid / 50, k = (tid % 50) * 4;
        unsigned int u01 = (unsigned int)f2bf(hq.x) | ((unsigned int)f2bf(hq.y) << 16);
        unsigned int u23 = (unsigned int)f2bf(hq.z) | ((unsigned int)f2bf(hq.w) << 16);
        *(uint2*)&hbf[hbf_idx(b, k)] = (uint2){u01, u23};
    }
    if (tid < BB) {
        float run = 0.f;
        for (int i = 0; i < TT; ++i) {
            zr_s[tid][i] = (run == 0.f) ? 1.f : 0.f;
            run += guid_s[tid][i];
        }
    }
    __syncthreads();

    bool vB = tid < 500;
    int bB = vB ? tid / 50 : 0;
    int cB = vB ? tid % 50 : 0;
    const float* xwbase = XW + bB * (TT * G3) + cB * 4;

    #pragma unroll 1
    for (int i = 0; i < TT; ++i) {
        // ---- A-frags ----
        bf16x8 ahi[NKS];
        #pragma unroll
        for (int ks = 0; ks < NKS; ++ks)
            ahi[ks] = *(const bf16x8*)&hbf[hbf_idx(ar, ks * 32 + kg * 8)];
        // ---- sc MFMA (always on: anchors ahi in all modes) ----
        f32x4 sch = (f32x4){0.f, 0.f, 0.f, 0.f};
        f32x4 scl = (f32x4){0.f, 0.f, 0.f, 0.f};
        #pragma unroll
        for (int ks = 0; ks < NKS; ++ks) {
            sch = __builtin_amdgcn_mfma_f32_16x16x32_bf16(ahi[ks], wh_lds[0][ks][lane], sch, 0, 0, 0);
            scl = __builtin_amdgcn_mfma_f32_16x16x32_bf16(ahi[ks], wh_lds[1][ks][lane], scl, 0, 0, 0);
        }
        // ---- B2 MFMAs (ablated in MODE 2; ghf writes kept) ----
        {
            f32x4 acc[SLOTS];
            if (MODE != 2) {
                #pragma unroll
                for (int s = 0; s < RSLOTS; ++s) {
                    acc[s] = (f32x4){0.f, 0.f, 0.f, 0.f};
                    #pragma unroll
                    for (int ks = 0; ks < NKS; ++ks)
                        acc[s] = __builtin_amdgcn_mfma_f32_16x16x32_bf16(ahi[ks], bfr[s][ks], acc[s], 0, 0, 0);
                }
                acc[RSLOTS] = (f32x4){0.f, 0.f, 0.f, 0.f};
                #pragma unroll
                for (int ks = 0; ks < NKS; ++ks) {
                    bf16x8 bw = wlds[wv][ks][lane];
                    acc[RSLOTS] = __builtin_amdgcn_mfma_f32_16x16x32_bf16(ahi[ks], bw, acc[RSLOTS], 0, 0, 0);
                }
            } else {
                #pragma unroll
                for (int s = 0; s < SLOTS; ++s) acc[s] = (f32x4){0.f, 0.f, 0.f, 0.f};
            }
            int xr = (kg & 3) << 2;
            int base0 = 40 * ar + 5 * wv;
            #pragma unroll
            for (int r = 0; r < 4; ++r) {
                int b = 4 * kg + r;
                if (b < BB) {
                    int base = b * GHW + base0;
                    #pragma unroll
                    for (int s = 0; s < SLOTS; ++s)
                        ghf[(base + s) ^ xr] = acc[s][r];
                }
            }
        }
        // ---- softmax over b (reduce ablated in MODE 3) ----
        {
            int t = ar;
            float vv[4], mx = -3e38f;
            #pragma unroll
            for (int r = 0; r < 4; ++r) {
                int b = 4 * kg + r;
                float val = -3e38f;
                if (b < BB && t < TT) {
                    float ge = (t == i) ? 1.f : (zr_s[b][i] != 0.f ? 1.f : guid_s[b][t]);
                    val = ge * xw_s[b][t] + sch[r] + scl[r] + bh_s[t];
                }
                vv[r] = val;
                mx = fmaxf(mx, val);
            }
            if (MODE != 3) {
                mx = fmaxf(mx, __shfl_xor(mx, 16));
                mx = fmaxf(mx, __shfl_xor(mx, 32));
                float ee[4], sum = 0.f;
                #pragma unroll
                for (int r = 0; r < 4; ++r) {
                    ee[r] = (vv[r] > -1e37f) ? __expf(vv[r] - mx) : 0.f;
                    sum += ee[r];
                }
                sum += __shfl_xor(sum, 16);
                sum += __shfl_xor(sum, 32);
                float inv = 1.f / sum;
                #pragma unroll
                for (int r = 0; r < 4; ++r) {
                    int b = 4 * kg + r;
                    if (b < BB && t < TT) a_w[wv][t][b] = (t <= i) ? ee[r] * inv : 0.f;
                }
            } else {
                #pragma unroll
                for (int r = 0; r < 4; ++r) {
                    int b = 4 * kg + r;
                    if (b < BB && t < TT) a_w[wv][t][b] = (t <= i) ? vv[r] * 0.01f : 0.f;
                }
            }
        }
        // ---- B1 (ablated in MODE 1): runtime-trip, R9 form ----
        float4 gi_r = (float4){0.f, 0.f, 0.f, 0.f};
        float4 gi_z = gi_r, gi_n = gi_r;
        if (MODE != 1 && vB) {
            float a12[TT];
            #pragma unroll
            for (int t = 0; t < TT; ++t) a12[t] = a_w[wv][t][bB];
            for (int t = 0; t <= i; ++t) {
                float aa = a12[t];
                float4 vr = *(const float4*)(xwbase + t * G3);
                float4 vz = *(const float4*)(xwbase + t * G3 + HH);
                float4 vn = *(const float4*)(xwbase + t * G3 + 2 * HH);
                gi_r.x += aa * vr.x; gi_r.y += aa * vr.y; gi_r.z += aa * vr.z; gi_r.w += aa * vr.w;
                gi_z.x += aa * vz.x; gi_z.y += aa * vz.y; gi_z.z += aa * vz.z; gi_z.w += aa * vz.w;
                gi_n.x += aa * vn.x; gi_n.y += aa * vn.y; gi_n.z += aa * vn.z; gi_n.w += aa * vn.w;
            }
        }
        __syncthreads();   // bar1: ghf ready

        // ---- P3: GRU update; gi in regs, gh from ghf; hbf refresh ----
        if (vB) {
            int b = bB, k = cB * 4;
            int xr = ((b >> 2) & 3) << 2;
            float4 ghr = *(const float4*)&ghf[(b * GHW + k) ^ xr];
            float4 ghz = *(const float4*)&ghf[(b * GHW + k + HH) ^ xr];
            float4 ghn = *(const float4*)&ghf[(b * GHW + k + 2 * HH) ^ xr];
            float4 br4 = *(const float4*)&bsum_s[k];
            float4 bz4 = *(const float4*)&bsum_s[k + HH];
            float4 bni = *(const float4*)&bihn_s[k];
            float4 bnh = *(const float4*)&bhhn_s[k];
            float4 hn;
            float* pgir = (float*)&gi_r; float* pgiz = (float*)&gi_z; float* pgin = (float*)&gi_n;
            float* pghr = (float*)&ghr;  float* pghz = (float*)&ghz;  float* pghn = (float*)&ghn;
            float* pbr = (float*)&br4;   float* pbz = (float*)&bz4;
            float* pbi = (float*)&bni;   float* pbh = (float*)&bnh;
            float* ph  = (float*)&hq;    float* phn = (float*)&hn;
            #pragma unroll
            for (int e = 0; e < 4; ++e) {
                float r = 1.f / (1.f + __expf(-(pgir[e] + pghr[e] + pbr[e])));
                float z = 1.f / (1.f + __expf(-(pgiz[e] + pghz[e] + pbz[e])));
                float xx = pgin[e] + pbi[e] + r * (pghn[e] + pbh[e]);
                float e2 = __expf(2.f * xx);
                float n = 1.f - 2.f / (e2 + 1.f);
                phn[e] = (1.f - z) * n + z * ph[e];
            }
            hq = hn;
            unsigned int u01 = (unsigned int)f2bf(hn.x) | ((unsigned int)f2bf(hn.y) << 16);
            unsigned int u23 = (unsigned int)f2bf(hn.z) | ((unsigned int)f2bf(hn.w) << 16);
            *(uint2*)&hbf[hbf_idx(b, k)] = (uint2){u01, u23};
        }
        __syncthreads();   // bar2: hbf ready for next step
    }

    if (vB) *(float4*)(out + bB * HH + cB * 4) = hq;
}

extern "C" void kernel_launch(void* const* d_in, const int* in_sizes, int n_in,
                              void* d_out, int out_size, void* d_ws, size_t ws_size,
                              hipStream_t stream) {
    (void)in_sizes; (void)n_in; (void)out_size; (void)ws_size;
    const float* x    = (const float*)d_in[0];
    const float* guid = (const float*)d_in[1];
    const float* wx   = (const float*)d_in[2];
    const float* Wh   = (const float*)d_in[3];
    const float* bh   = (const float*)d_in[4];
    const float* W_ih = (const float*)d_in[5];
    const float* W_hh = (const float*)d_in[6];
    const float* b_ih = (const float*)d_in[7];
    const float* b_hh = (const float*)d_in[8];
    const float* h0   = (const float*)d_in[9];
    float* ws  = (float*)d_ws;
    float* out = (float*)d_out;

    hipLaunchKernelGGL(prep_kernel, dim3(100), dim3(256), 0, stream,
                       x, wx, W_ih, W_hh, Wh, ws);
    // Ablation probes (deterministic dummies; out fully overwritten by MODE=0 below)
    hipLaunchKernelGGL((recurrence_kernel<1>), dim3(1), dim3(512), 0, stream,
                       guid, bh, b_ih, b_hh, h0, ws, out);
    hipLaunchKernelGGL((recurrence_kernel<2>), dim3(1), dim3(512), 0, stream,
                       guid, bh, b_ih, b_hh, h0, ws, out);
    hipLaunchKernelGGL((recurrence_kernel<3>), dim3(1), dim3(512), 0, stream,
                       guid, bh, b_ih, b_hh, h0, ws, out);
    // The real kernel — runs last, defines out
    hipLaunchKernelGGL((recurrence_kernel<0>), dim3(1), dim3(512), 0, stream,
                       guid, bh, b_ih, b_hh, h0, ws, out);
}

// Round 12
// 153.750 us; speedup vs baseline: 1.5870x; 1.5870x over previous
//
#include <hip/hip_runtime.h>
#include <math.h>

#define BB 10
#define TT 12
#define FF 500
#define HH 200
#define G3 600
#define KP 224      // padded K for h rows (7*32)
#define NKS 7       // K-steps of 32
#define NTIL 48     // j-tiles: 8 waves * 6 slots
#define WVS 8

// j-permutation (prep & K2 must agree):
//   tile tau = wv*6 + s, s = pair*3 + g  (g=s%3 gate, pair=s/3)
//   col n -> j = g*200 + K,  K = n*16 + wv*2 + pair   (valid iff K<200)

// ws layout (float units):
#define WS_XWPB 0        // XWP bf16 [12][200][3][12] = 86400 ushorts = 43200 floats
#define WS_XWV  43200    // xw [120] fp32
#define WS_FRAG 43328    // W_hh B-frags: 48 tiles * 7 ks * 64 lanes * 16B = 86016 dwords
#define WS_WHF  129344   // Wh hi/lo B-frags: 14 * 64 * 16B = 3584 dwords

typedef __attribute__((ext_vector_type(8))) short bf16x8;
typedef __attribute__((ext_vector_type(4))) float f32x4;

__device__ __forceinline__ unsigned short f2bf(float f) {
    unsigned int u = __float_as_uint(f);
    u = (u + 0x7fffu + ((u >> 16) & 1u)) >> 16;
    return (unsigned short)u;
}
__device__ __forceinline__ float bf2f(unsigned short h) {
    return __uint_as_float(((unsigned int)h) << 16);
}

// ---------------- K1: XWP bf16, xw, W_hh B-frags (triple-layout), Wh hi/lo frags ----
__global__ __launch_bounds__(256) void prep_kernel(
        const float* __restrict__ x, const float* __restrict__ wx,
        const float* __restrict__ W_ih, const float* __restrict__ W_hh,
        const float* __restrict__ Wh, float* __restrict__ ws) {
    int bl = blockIdx.x, tid = threadIdx.x;
    if (bl < 75) {
        // XW[b][t][j] -> XWP[t][K][g][b] (bf16), j chunk [bl*8, bl*8+8)
        __shared__ __align__(16) float wsm[8][FF];
        int j0 = bl * 8;
        for (int idx = tid; idx < 8 * FF; idx += 256)
            wsm[idx / FF][idx % FF] = W_ih[(j0 + idx / FF) * FF + (idx % FF)];
        __syncthreads();
        unsigned short* xwpb = (unsigned short*)ws;
        for (int p = tid; p < BB * TT * 8; p += 256) {
            int bt = p >> 3, jj = p & 7;
            const float4* xr = (const float4*)(x + bt * FF);
            const float4* wr = (const float4*)&wsm[jj][0];
            float acc = 0.f;
            for (int c = 0; c < FF / 4; ++c) {
                float4 a = xr[c], b = wr[c];
                acc += a.x * b.x + a.y * b.y + a.z * b.z + a.w * b.w;
            }
            int t = bt % TT, b = bt / TT;
            int j = j0 + jj, g = j / 200, K = j % 200;
            xwpb[((t * 200 + K) * 3 + g) * 12 + b] = f2bf(acc);
        }
    } else if (bl < 99) {
        // W_hh B-frags, 24 blocks * 3584 dwords; d = ((tau*7+ks)*64+lane)*4+v
        unsigned int* fr = (unsigned int*)(ws + WS_FRAG);
        int base = (bl - 75) * 3584;
        for (int q = tid; q < 3584; q += 256) {
            int d = base + q;
            int v = d & 3, lane = (d >> 2) & 63, pk = d >> 8;
            int ks = pk % NKS, tau = pk / NKS;
            int wv_ = tau / 6, s = tau % 6, g = s % 3, pr = s / 3;
            int n = lane & 15;
            int K = n * 16 + wv_ * 2 + pr;
            int kq = ks * 32 + (lane >> 4) * 8 + 2 * v;
            unsigned int w = 0;
            if (K < 200 && kq < HH) {
                int j = g * 200 + K;
                w = (unsigned int)f2bf(W_hh[j * HH + kq]) |
                    ((unsigned int)f2bf(W_hh[j * HH + kq + 1]) << 16);
            }
            fr[d] = w;
        }
    } else if (bl < 107) {
        // xw[bt] = x[bt]·wx
        int dte = (bl - 99) * 15 + (tid >> 4), l = tid & 15;
        if (tid < 240) {
            float p = 0.f;
            for (int f = l; f < FF; f += 16) p += x[dte * FF + f] * wx[f];
            p += __shfl_xor(p, 8);
            p += __shfl_xor(p, 4);
            p += __shfl_xor(p, 2);
            p += __shfl_xor(p, 1);
            if (l == 0) ws[WS_XWV + dte] = p;
        }
    } else {
        // Wh hi/lo B-frags: d = ((ks*2+qq)*64+lane)*4+v ; col n = t = lane&15
        unsigned int* fr = (unsigned int*)(ws + WS_WHF);
        for (int d = tid; d < 3584; d += 256) {
            int v = d & 3, lane = (d >> 2) & 63, pk = d >> 8;
            int qq = pk & 1, ks = pk >> 1;
            int t = lane & 15, k = ks * 32 + (lane >> 4) * 8 + 2 * v;
            unsigned int w = 0;
            if (t < TT && k < HH) {
                float f0 = Wh[t * HH + k], f1 = Wh[t * HH + k + 1];
                if (qq == 0) {
                    w = (unsigned int)f2bf(f0) | ((unsigned int)f2bf(f1) << 16);
                } else {
                    float l0 = f0 - bf2f(f2bf(f0)), l1 = f1 - bf2f(f2bf(f1));
                    w = (unsigned int)f2bf(l0) | ((unsigned int)f2bf(l1) << 16);
                }
            }
            fr[d] = w;
        }
    }
}

// hbf: bf16 h [16 rows(b)][KP], XOR-swizzled (ushort idx ^ (b&7)<<3)
__device__ __forceinline__ int hbf_idx(int r, int k) {
    return (r * KP + k) ^ ((r & 7) << 3);
}

// ---------------- K2: 12-step recurrence, 8 waves, ONE barrier per step ----------------
__global__ __attribute__((amdgpu_waves_per_eu(2, 2))) __launch_bounds__(512)
void recurrence_kernel(
        const float* __restrict__ guidance, const float* __restrict__ bh,
        const float* __restrict__ b_ih, const float* __restrict__ b_hh,
        const float* __restrict__ h0, const float* __restrict__ ws,
        float* __restrict__ out) {
    const unsigned short* XWPB = (const unsigned short*)ws;
    const float* xww = ws + WS_XWV;

    __shared__ __align__(16) unsigned short hbf[16 * KP];   // 7 KB
    __shared__ __align__(16) bf16x8 wlds2[WVS][2][NKS][64]; // 114.7 KB (2 tiles/wave)
    __shared__ __align__(16) bf16x8 wh_lds[2][NKS][64];     // 14.3 KB
    __shared__ float guid_s[BB][TT], zr_s[BB][TT], xw_s[BB][TT];
    __shared__ __align__(16) float a_w[WVS][TT][16];        // 6 KB (b-contig, padded)
    __shared__ float bh_s[TT];

    int tid = threadIdx.x, wv = tid >> 6, lane = tid & 63;
    int ar = lane & 15, kg = lane >> 4;

    // --- W_hh B-fragments: 4 tiles/wave -> regs, 2 tiles/wave -> LDS ---
    bf16x8 bfr[4][NKS];
    {
        const bf16x8* fragp = (const bf16x8*)(ws + WS_FRAG);
        #pragma unroll
        for (int s = 0; s < 4; ++s)
            #pragma unroll
            for (int ks = 0; ks < NKS; ++ks)
                bfr[s][ks] = fragp[((wv * 6 + s) * NKS + ks) * 64 + lane];
        #pragma unroll
        for (int s2 = 0; s2 < 2; ++s2)
            #pragma unroll
            for (int ks = 0; ks < NKS; ++ks)
                wlds2[wv][s2][ks][lane] = fragp[((wv * 6 + 4 + s2) * NKS + ks) * 64 + lane];
        const bf16x8* whp = (const bf16x8*)(ws + WS_WHF);
        for (int u = tid; u < 2 * NKS * 64; u += 512) {
            int l = u & 63, pk = u >> 6;
            wh_lds[pk & 1][pk >> 1][l] = whp[u];
        }
    }
    // --- LDS init ---
    if (tid < BB * TT) {
        guid_s[tid / TT][tid % TT] = guidance[tid];
        xw_s[tid / TT][tid % TT]   = xww[tid];
    }
    if (tid < TT) bh_s[tid] = bh[tid];
    for (int idx = tid; idx < 16 * KP / 2; idx += 512) ((unsigned int*)hbf)[idx] = 0;
    for (int idx = tid; idx < WVS * TT * 16; idx += 512) ((float*)a_w)[idx] = 0.f;

    // --- per-lane geometry: this lane owns (b = 4kg+r) x (K = Kc, Kc+1) ---
    int Kp0 = ar * 16 + wv * 2;          // even; Kp1 = Kp0+1
    bool ok = Kp0 < 200;
    int Kc = ok ? Kp0 : 0;
    // per-lane biases (reg-resident for whole kernel)
    float2 br2, bz2, bni2, bnh2;
    br2.x = b_ih[Kc] + b_hh[Kc];             br2.y = b_ih[Kc + 1] + b_hh[Kc + 1];
    bz2.x = b_ih[200 + Kc] + b_hh[200 + Kc]; bz2.y = b_ih[201 + Kc] + b_hh[201 + Kc];
    bni2.x = b_ih[400 + Kc];  bni2.y = b_ih[401 + Kc];
    bnh2.x = b_hh[400 + Kc];  bnh2.y = b_hh[401 + Kc];
    // per-lane h state: hpx/hpy[r] = h[4kg+r][Kc], h[4kg+r][Kc+1]
    float hpx[4], hpy[4];
    #pragma unroll
    for (int r = 0; r < 4; ++r) {
        int b = 4 * kg + r;
        if (ok && b < BB) {
            float2 h2 = *(const float2*)(h0 + b * HH + Kc);
            hpx[r] = h2.x; hpy[r] = h2.y;
        } else { hpx[r] = 0.f; hpy[r] = 0.f; }
    }
    __syncthreads();
    // hbf <- h0 (full coverage via 500-thread path)
    if (tid < 500) {
        int b = tid / 50, k = (tid % 50) * 4;
        float4 h4 = *(const float4*)(h0 + b * HH + k);
        unsigned int u01 = (unsigned int)f2bf(h4.x) | ((unsigned int)f2bf(h4.y) << 16);
        unsigned int u23 = (unsigned int)f2bf(h4.z) | ((unsigned int)f2bf(h4.w) << 16);
        *(uint2*)&hbf[hbf_idx(b, k)] = (uint2){u01, u23};
    }
    if (tid < BB) {
        float run = 0.f;
        for (int i = 0; i < TT; ++i) {
            zr_s[tid][i] = (run == 0.f) ? 1.f : 0.f;
            run += guid_s[tid][i];
        }
    }
    __syncthreads();

    #pragma unroll 1
    for (int i = 0; i < TT; ++i) {
        // ---- A-frags (from hbf, post-barrier) ----
        bf16x8 ahi[NKS];
        #pragma unroll
        for (int ks = 0; ks < NKS; ++ks)
            ahi[ks] = *(const bf16x8*)&hbf[hbf_idx(ar, ks * 32 + kg * 8)];
        // ---- sc MFMA (2 parallel chains, hi/lo Wh; redundant on every wave) ----
        f32x4 sch = (f32x4){0.f, 0.f, 0.f, 0.f};
        f32x4 scl = (f32x4){0.f, 0.f, 0.f, 0.f};
        #pragma unroll
        for (int ks = 0; ks < NKS; ++ks) {
            sch = __builtin_amdgcn_mfma_f32_16x16x32_bf16(ahi[ks], wh_lds[0][ks][lane], sch, 0, 0, 0);
            scl = __builtin_amdgcn_mfma_f32_16x16x32_bf16(ahi[ks], wh_lds[1][ks][lane], scl, 0, 0, 0);
        }
        // ---- B2 MFMAs: acc[s] = gh gate (g=s%3) at K = Kc + s/3, b = 4kg+r ----
        f32x4 acc[6];
        #pragma unroll
        for (int s = 0; s < 4; ++s) {
            acc[s] = (f32x4){0.f, 0.f, 0.f, 0.f};
            #pragma unroll
            for (int ks = 0; ks < NKS; ++ks)
                acc[s] = __builtin_amdgcn_mfma_f32_16x16x32_bf16(ahi[ks], bfr[s][ks], acc[s], 0, 0, 0);
        }
        #pragma unroll
        for (int s2 = 0; s2 < 2; ++s2) {
            acc[4 + s2] = (f32x4){0.f, 0.f, 0.f, 0.f};
            #pragma unroll
            for (int ks = 0; ks < NKS; ++ks) {
                bf16x8 bw = wlds2[wv][s2][ks][lane];
                acc[4 + s2] = __builtin_amdgcn_mfma_f32_16x16x32_bf16(ahi[ks], bw, acc[4 + s2], 0, 0, 0);
            }
        }
        // ---- softmax over b (per t = ar); result wave-local in a_w ----
        {
            int t = ar;
            float vv[4], mx = -3e38f;
            #pragma unroll
            for (int r = 0; r < 4; ++r) {
                int b = 4 * kg + r;
                float val = -3e38f;
                if (b < BB && t < TT) {
                    float ge = (t == i) ? 1.f : (zr_s[b][i] != 0.f ? 1.f : guid_s[b][t]);
                    val = ge * xw_s[b][t] + sch[r] + scl[r] + bh_s[t];
                }
                vv[r] = val;
                mx = fmaxf(mx, val);
            }
            mx = fmaxf(mx, __shfl_xor(mx, 16));
            mx = fmaxf(mx, __shfl_xor(mx, 32));
            float ee[4], sum = 0.f;
            #pragma unroll
            for (int r = 0; r < 4; ++r) {
                ee[r] = (vv[r] > -1e37f) ? __expf(vv[r] - mx) : 0.f;
                sum += ee[r];
            }
            sum += __shfl_xor(sum, 16);
            sum += __shfl_xor(sum, 32);
            float inv = 1.f / sum;
            #pragma unroll
            for (int r = 0; r < 4; ++r) {
                int b = 4 * kg + r;
                if (b < BB && t < TT) a_w[wv][t][b] = (t <= i) ? ee[r] * inv : 0.f;
            }
        }
        // ---- B1: gi[s] (b-quad float4) from bf16 XWP[t][K][g][b] ----
        f32x4 gi[6];
        #pragma unroll
        for (int s = 0; s < 6; ++s) gi[s] = (f32x4){0.f, 0.f, 0.f, 0.f};
        {
            const unsigned short* xb = XWPB + (Kc * 3) * 12 + 4 * kg;
            for (int t = 0; t <= i; ++t) {
                float4 a4 = *(const float4*)&a_w[wv][t][4 * kg];
                const unsigned short* bt_ = xb + t * (200 * 36);
                #pragma unroll
                for (int pr = 0; pr < 2; ++pr)
                    #pragma unroll
                    for (int g = 0; g < 3; ++g) {
                        int s = pr * 3 + g;
                        uint2 u = *(const uint2*)(bt_ + pr * 36 + g * 12);
                        float f0 = __uint_as_float(u.x << 16);
                        float f1 = __uint_as_float(u.x & 0xffff0000u);
                        float f2 = __uint_as_float(u.y << 16);
                        float f3 = __uint_as_float(u.y & 0xffff0000u);
                        gi[s].x += a4.x * f0; gi[s].y += a4.y * f1;
                        gi[s].z += a4.z * f2; gi[s].w += a4.w * f3;
                    }
            }
        }
        // ---- P3: GRU update fully in-register; write hbf for next step ----
        #pragma unroll
        for (int r = 0; r < 4; ++r) {
            int b = 4 * kg + r;
            float rg0 = 1.f / (1.f + __expf(-(gi[0][r] + acc[0][r] + br2.x)));
            float z0  = 1.f / (1.f + __expf(-(gi[1][r] + acc[1][r] + bz2.x)));
            float xx0 = gi[2][r] + bni2.x + rg0 * (acc[2][r] + bnh2.x);
            float e20 = __expf(2.f * xx0);
            float n0  = 1.f - 2.f / (e20 + 1.f);
            float h0n = (1.f - z0) * n0 + z0 * hpx[r];
            float rg1 = 1.f / (1.f + __expf(-(gi[3][r] + acc[3][r] + br2.y)));
            float z1  = 1.f / (1.f + __expf(-(gi[4][r] + acc[4][r] + bz2.y)));
            float xx1 = gi[5][r] + bni2.y + rg1 * (acc[5][r] + bnh2.y);
            float e21 = __expf(2.f * xx1);
            float n1  = 1.f - 2.f / (e21 + 1.f);
            float h1n = (1.f - z1) * n1 + z1 * hpy[r];
            hpx[r] = h0n; hpy[r] = h1n;
            if (ok && b < BB) {
                unsigned int uu = (unsigned int)f2bf(h0n) | ((unsigned int)f2bf(h1n) << 16);
                *(unsigned int*)&hbf[hbf_idx(b, Kc)] = uu;
            }
        }
        __syncthreads();   // single barrier: hbf ready for next step
    }

    #pragma unroll
    for (int r = 0; r < 4; ++r) {
        int b = 4 * kg + r;
        if (ok && b < BB) *(float2*)(out + b * HH + Kc) = (float2){hpx[r], hpy[r]};
    }
}

extern "C" void kernel_launch(void* const* d_in, const int* in_sizes, int n_in,
                              void* d_out, int out_size, void* d_ws, size_t ws_size,
                              hipStream_t stream) {
    (void)in_sizes; (void)n_in; (void)out_size; (void)ws_size;
    const float* x    = (const float*)d_in[0];
    const float* guid = (const float*)d_in[1];
    const float* wx   = (const float*)d_in[2];
    const float* Wh   = (const float*)d_in[3];
    const float* bh   = (const float*)d_in[4];
    const float* W_ih = (const float*)d_in[5];
    const float* W_hh = (const float*)d_in[6];
    const float* b_ih = (const float*)d_in[7];
    const float* b_hh = (const float*)d_in[8];
    const float* h0   = (const float*)d_in[9];
    float* ws  = (float*)d_ws;
    float* out = (float*)d_out;

    hipLaunchKernelGGL(prep_kernel, dim3(108), dim3(256), 0, stream,
                       x, wx, W_ih, W_hh, Wh, ws);
    hipLaunchKernelGGL(recurrence_kernel, dim3(1), dim3(512), 0, stream,
                       guid, bh, b_ih, b_hh, h0, ws, out);
}

// Round 13
// 83.901 us; speedup vs baseline: 2.9082x; 1.8325x over previous
//
#include <hip/hip_runtime.h>
#include <math.h>

#define BB 10
#define TT 12
#define FF 500
#define HH 200
#define G3 600
#define KP 224      // padded K for h (7*32)
#define NKS 7       // K-steps of 32
#define SLOTS 5     // j-tiles per wave (8 waves * 5 = 40); 4 in regs + 1 in LDS
#define RSLOTS 4
#define GHW 648     // ghf row stride in floats

// ws layout (float units):
#define WS_XW   0        // XW [120][600] fp32
#define WS_XWV  72000    // xw [120]
#define WS_FRAG 72128    // W_hh B-frags: 40 tiles * 7 ks * 64 lanes * 16B = 71680 dwords
#define WS_WHF  143808   // Wh hi/lo B-frags: 14 * 64 * 16B = 3584 dwords

typedef __attribute__((ext_vector_type(8))) short bf16x8;
typedef __attribute__((ext_vector_type(4))) float f32x4;

__device__ __forceinline__ unsigned short f2bf(float f) {
    unsigned int u = __float_as_uint(f);
    u = (u + 0x7fffu + ((u >> 16) & 1u)) >> 16;
    return (unsigned short)u;
}
__device__ __forceinline__ float bf2f(unsigned short h) {
    return __uint_as_float(((unsigned int)h) << 16);
}
__device__ __forceinline__ void cvt_hilo(const float* v, bf16x8& hi, bf16x8& lo) {
    #pragma unroll
    for (int e = 0; e < 8; ++e) {
        unsigned short h = f2bf(v[e]);
        hi[e] = (short)h;
        lo[e] = (short)f2bf(v[e] - bf2f(h));
    }
}

// ---------------- K1: XW via MFMA (hi/lo), xw, W_hh B-frags, Wh hi/lo frags ----------
// XW-GEMM: M=120 (x rows b*12+t), N=600 (W_ih rows j), K=500 pad 512.
// A[m][k]=x[m][k]: lane m=lane&15, k=ks*32+(lane>>4)*8+e.  B[k][n]=W_ih[n][k]: n=lane&15.
// C/D: col(n)=lane&15, row(m)=(lane>>4)*4+r  [m89-verified map].
__global__ __launch_bounds__(256) void prep_kernel(
        const float* __restrict__ x, const float* __restrict__ wx,
        const float* __restrict__ W_ih, const float* __restrict__ W_hh,
        const float* __restrict__ Wh, float* __restrict__ ws) {
    int bl = blockIdx.x, tid = threadIdx.x;
    int wv = tid >> 6, lane = tid & 63;
    int ar = lane & 15, kg = lane >> 4;
    if (bl < 38) {
        // one 16-wide n-strip; 4 waves x 2 m-tiles each
        int n0 = bl * 16;
        int nj = n0 + ar;
        bool nok = nj < G3;
        const float* wrow = W_ih + (nok ? nj : 0) * FF;
        #pragma unroll
        for (int half = 0; half < 2; ++half) {
            int mt = wv + half * 4;                 // m-tile 0..7
            int arow = mt * 16 + ar;
            const float* xrow = x + (arow < 120 ? arow : 119) * FF;
            f32x4 a0 = (f32x4){0.f, 0.f, 0.f, 0.f}, a1 = a0, a2 = a0;
            #pragma unroll
            for (int ks = 0; ks < 16; ++ks) {
                int f0 = ks * 32 + kg * 8;
                float xv[8], wv8[8];
                if (f0 + 8 <= FF) {
                    *(float4*)&xv[0]  = *(const float4*)(xrow + f0);
                    *(float4*)&xv[4]  = *(const float4*)(xrow + f0 + 4);
                    *(float4*)&wv8[0] = *(const float4*)(wrow + f0);
                    *(float4*)&wv8[4] = *(const float4*)(wrow + f0 + 4);
                } else {
                    #pragma unroll
                    for (int e = 0; e < 8; ++e) {
                        bool okf = (f0 + e) < FF;
                        xv[e]  = okf ? xrow[f0 + e] : 0.f;
                        wv8[e] = okf ? wrow[f0 + e] : 0.f;
                    }
                }
                bf16x8 xhi, xlo, whi, wlo;
                cvt_hilo(xv, xhi, xlo);
                cvt_hilo(wv8, whi, wlo);
                a0 = __builtin_amdgcn_mfma_f32_16x16x32_bf16(xhi, whi, a0, 0, 0, 0);
                a1 = __builtin_amdgcn_mfma_f32_16x16x32_bf16(xlo, whi, a1, 0, 0, 0);
                a2 = __builtin_amdgcn_mfma_f32_16x16x32_bf16(xhi, wlo, a2, 0, 0, 0);
            }
            #pragma unroll
            for (int r = 0; r < 4; ++r) {
                int bt = mt * 16 + kg * 4 + r;
                if (bt < 120 && nok)
                    ws[WS_XW + bt * G3 + nj] = a0[r] + a1[r] + a2[r];
            }
        }
    } else if (bl < 54) {
        // W_hh B-frags: dword d = ((tile*NKS+ks)*64+lane)*4+v ; k = ks*32+(lane>>4)*8+2v
        unsigned int* fr = (unsigned int*)(ws + WS_FRAG);
        int base = (bl - 38) * 4480;
        for (int q = tid; q < 4480; q += 256) {
            int d = base + q;
            int v = d & 3, ln = (d >> 2) & 63, pk = d >> 8;
            int ks = pk % NKS, tile = pk / NKS;
            int n = ln & 15;
            int k = ks * 32 + (ln >> 4) * 8 + 2 * v;
            unsigned int w = 0;
            if (k < HH && n < 15) {
                int j = 40 * n + tile;   // < 600
                w = (unsigned int)f2bf(W_hh[j * HH + k]) |
                    ((unsigned int)f2bf(W_hh[j * HH + k + 1]) << 16);
            }
            fr[d] = w;
        }
    } else if (bl < 62) {
        // xw[bt] = x[bt]·wx
        int dte = (bl - 54) * 15 + (tid >> 4), l = tid & 15;
        if (tid < 240) {
            float p = 0.f;
            for (int f = l; f < FF; f += 16) p += x[dte * FF + f] * wx[f];
            p += __shfl_xor(p, 8);
            p += __shfl_xor(p, 4);
            p += __shfl_xor(p, 2);
            p += __shfl_xor(p, 1);
            if (l == 0) ws[WS_XWV + dte] = p;
        }
    } else {
        // Wh hi/lo B-frags: d = ((ks*2+qq)*64+lane)*4+v ; n-col = t = lane&15
        unsigned int* fr = (unsigned int*)(ws + WS_WHF);
        for (int d = tid; d < 3584; d += 256) {
            int v = d & 3, ln = (d >> 2) & 63, pk = d >> 8;
            int qq = pk & 1, ks = pk >> 1;
            int t = ln & 15, k = ks * 32 + (ln >> 4) * 8 + 2 * v;
            unsigned int w = 0;
            if (t < TT && k < HH) {
                float f0 = Wh[t * HH + k], f1 = Wh[t * HH + k + 1];
                if (qq == 0) {
                    w = (unsigned int)f2bf(f0) | ((unsigned int)f2bf(f1) << 16);
                } else {
                    float l0 = f0 - bf2f(f2bf(f0)), l1 = f1 - bf2f(f2bf(f1));
                    w = (unsigned int)f2bf(l0) | ((unsigned int)f2bf(l1) << 16);
                }
            }
            fr[d] = w;
        }
    }
}

// hbf: bf16 h [16 rows(b)][KP], XOR-swizzled (ushort idx ^ (b&7)<<3)
__device__ __forceinline__ int hbf_idx(int r, int k) {
    return (r * KP + k) ^ ((r & 7) << 3);
}

// ---------------- K2: single-block 12-step recurrence, 8 waves (R9-verbatim) --------
__global__ __attribute__((amdgpu_waves_per_eu(2, 2))) __launch_bounds__(512)
void recurrence_kernel(
        const float* __restrict__ guidance, const float* __restrict__ bh,
        const float* __restrict__ b_ih, const float* __restrict__ b_hh,
        const float* __restrict__ h0, const float* __restrict__ ws,
        float* __restrict__ out) {
    const float* XW  = ws + WS_XW;
    const float* xww = ws + WS_XWV;

    __shared__ __align__(16) float ghf[16 * GHW];           // 41.5 KB
    __shared__ __align__(16) unsigned short hbf[16 * KP];   // 7 KB
    __shared__ __align__(16) bf16x8 wlds[8][NKS][64];       // 57 KB (1 tile/wave)
    __shared__ __align__(16) bf16x8 wh_lds[2][NKS][64];     // 14 KB
    __shared__ __align__(16) float bsum_s[2 * HH];          // r,z gate bias sums
    __shared__ __align__(16) float bihn_s[HH];
    __shared__ __align__(16) float bhhn_s[HH];
    __shared__ float guid_s[BB][TT], zr_s[BB][TT], xw_s[BB][TT];
    __shared__ float a_w[8][TT][12];
    __shared__ float bh_s[TT];

    int tid = threadIdx.x, wv = tid >> 6, lane = tid & 63;
    int ar = lane & 15, kg = lane >> 4;

    // --- W_hh B-fragments: 4 tiles/wave -> regs (112), 1 tile/wave -> LDS ---
    bf16x8 bfr[RSLOTS][NKS];
    {
        const bf16x8* fragp = (const bf16x8*)(ws + WS_FRAG);
        #pragma unroll
        for (int s = 0; s < RSLOTS; ++s)
            #pragma unroll
            for (int ks = 0; ks < NKS; ++ks)
                bfr[s][ks] = fragp[((SLOTS * wv + s) * NKS + ks) * 64 + lane];
        #pragma unroll
        for (int ks = 0; ks < NKS; ++ks)
            wlds[wv][ks][lane] = fragp[((SLOTS * wv + RSLOTS) * NKS + ks) * 64 + lane];
        const bf16x8* whp = (const bf16x8*)(ws + WS_WHF);
        for (int u = tid; u < 2 * NKS * 64; u += 512) {
            int l = u & 63, pk = u >> 6;
            wh_lds[pk & 1][pk >> 1][l] = whp[u];
        }
    }
    // --- LDS init ---
    if (tid < BB * TT) {
        guid_s[tid / TT][tid % TT] = guidance[tid];
        xw_s[tid / TT][tid % TT]   = xww[tid];
    }
    for (int idx = tid; idx < 2 * HH; idx += 512) bsum_s[idx] = b_ih[idx] + b_hh[idx];
    for (int idx = tid; idx < HH; idx += 512) {
        bihn_s[idx] = b_ih[idx + 2 * HH];
        bhhn_s[idx] = b_hh[idx + 2 * HH];
    }
    if (tid < TT) bh_s[tid] = bh[tid];
    for (int idx = tid; idx < 16 * KP / 2; idx += 512) ((unsigned int*)hbf)[idx] = 0;
    float4 hq = (float4){0.f, 0.f, 0.f, 0.f};
    if (tid < 500) hq = *(const float4*)(h0 + (tid / 50) * HH + (tid % 50) * 4);
    __syncthreads();
    if (tid < 500) {
        int b = tid / 50, k = (tid % 50) * 4;
        unsigned int u01 = (unsigned int)f2bf(hq.x) | ((unsigned int)f2bf(hq.y) << 16);
        unsigned int u23 = (unsigned int)f2bf(hq.z) | ((unsigned int)f2bf(hq.w) << 16);
        *(uint2*)&hbf[hbf_idx(b, k)] = (uint2){u01, u23};
    }
    if (tid < BB) {
        float run = 0.f;
        for (int i = 0; i < TT; ++i) {
            zr_s[tid][i] = (run == 0.f) ? 1.f : 0.f;
            run += guid_s[tid][i];
        }
    }
    __syncthreads();

    bool vB = tid < 500;
    int bB = vB ? tid / 50 : 0;
    int cB = vB ? tid % 50 : 0;
    const float* xwbase = XW + bB * (TT * G3) + cB * 4;

    #pragma unroll 1
    for (int i = 0; i < TT; ++i) {
        // ---- A-frags ----
        bf16x8 ahi[NKS];
        #pragma unroll
        for (int ks = 0; ks < NKS; ++ks)
            ahi[ks] = *(const bf16x8*)&hbf[hbf_idx(ar, ks * 32 + kg * 8)];
        // ---- sc MFMA (2 parallel chains, hi/lo Wh) ----
        f32x4 sch = (f32x4){0.f, 0.f, 0.f, 0.f};
        f32x4 scl = (f32x4){0.f, 0.f, 0.f, 0.f};
        #pragma unroll
        for (int ks = 0; ks < NKS; ++ks) {
            sch = __builtin_amdgcn_mfma_f32_16x16x32_bf16(ahi[ks], wh_lds[0][ks][lane], sch, 0, 0, 0);
            scl = __builtin_amdgcn_mfma_f32_16x16x32_bf16(ahi[ks], wh_lds[1][ks][lane], scl, 0, 0, 0);
        }
        // ---- B2 MFMAs (independent; hide sc chain latency) ----
        {
            f32x4 acc[SLOTS];
            #pragma unroll
            for (int s = 0; s < RSLOTS; ++s) {
                acc[s] = (f32x4){0.f, 0.f, 0.f, 0.f};
                #pragma unroll
                for (int ks = 0; ks < NKS; ++ks)
                    acc[s] = __builtin_amdgcn_mfma_f32_16x16x32_bf16(ahi[ks], bfr[s][ks], acc[s], 0, 0, 0);
            }
            acc[RSLOTS] = (f32x4){0.f, 0.f, 0.f, 0.f};
            #pragma unroll
            for (int ks = 0; ks < NKS; ++ks) {
                bf16x8 bw = wlds[wv][ks][lane];
                acc[RSLOTS] = __builtin_amdgcn_mfma_f32_16x16x32_bf16(ahi[ks], bw, acc[RSLOTS], 0, 0, 0);
            }
            int xr = (kg & 3) << 2;
            int base0 = 40 * ar + 5 * wv;
            #pragma unroll
            for (int r = 0; r < 4; ++r) {
                int b = 4 * kg + r;
                if (b < BB) {
                    int base = b * GHW + base0;
                    #pragma unroll
                    for (int s = 0; s < SLOTS; ++s)
                        ghf[(base + s) ^ xr] = acc[s][r];
                }
            }
        }
        // ---- softmax over b (per t = ar), wave-local result ----
        {
            int t = ar;
            float vv[4], mx = -3e38f;
            #pragma unroll
            for (int r = 0; r < 4; ++r) {
                int b = 4 * kg + r;
                float val = -3e38f;
                if (b < BB && t < TT) {
                    float ge = (t == i) ? 1.f : (zr_s[b][i] != 0.f ? 1.f : guid_s[b][t]);
                    val = ge * xw_s[b][t] + sch[r] + scl[r] + bh_s[t];
                }
                vv[r] = val;
                mx = fmaxf(mx, val);
            }
            mx = fmaxf(mx, __shfl_xor(mx, 16));
            mx = fmaxf(mx, __shfl_xor(mx, 32));
            float ee[4], sum = 0.f;
            #pragma unroll
            for (int r = 0; r < 4; ++r) {
                ee[r] = (vv[r] > -1e37f) ? __expf(vv[r] - mx) : 0.f;
                sum += ee[r];
            }
            sum += __shfl_xor(sum, 16);
            sum += __shfl_xor(sum, 32);
            float inv = 1.f / sum;
            #pragma unroll
            for (int r = 0; r < 4; ++r) {
                int b = 4 * kg + r;
                if (b < BB && t < TT) a_w[wv][t][b] = (t <= i) ? ee[r] * inv : 0.f;
            }
        }
        // ---- B1: gi gates in REGISTERS; thread == P3 thread ----
        float4 gi_r = (float4){0.f, 0.f, 0.f, 0.f};
        float4 gi_z = gi_r, gi_n = gi_r;
        if (vB) {
            float a12[TT];
            #pragma unroll
            for (int t = 0; t < TT; ++t) a12[t] = a_w[wv][t][bB];
            for (int t = 0; t <= i; ++t) {
                float aa = a12[t];
                float4 vr = *(const float4*)(xwbase + t * G3);
                float4 vz = *(const float4*)(xwbase + t * G3 + HH);
                float4 vn = *(const float4*)(xwbase + t * G3 + 2 * HH);
                gi_r.x += aa * vr.x; gi_r.y += aa * vr.y; gi_r.z += aa * vr.z; gi_r.w += aa * vr.w;
                gi_z.x += aa * vz.x; gi_z.y += aa * vz.y; gi_z.z += aa * vz.z; gi_z.w += aa * vz.w;
                gi_n.x += aa * vn.x; gi_n.y += aa * vn.y; gi_n.z += aa * vn.z; gi_n.w += aa * vn.w;
            }
        }
        __syncthreads();   // bar1: ghf ready

        // ---- P3: GRU update; gi in regs, gh from ghf; hbf refresh ----
        if (vB) {
            int b = bB, k = cB * 4;
            int xr = ((b >> 2) & 3) << 2;
            float4 ghr = *(const float4*)&ghf[(b * GHW + k) ^ xr];
            float4 ghz = *(const float4*)&ghf[(b * GHW + k + HH) ^ xr];
            float4 ghn = *(const float4*)&ghf[(b * GHW + k + 2 * HH) ^ xr];
            float4 br4 = *(const float4*)&bsum_s[k];
            float4 bz4 = *(const float4*)&bsum_s[k + HH];
            float4 bni = *(const float4*)&bihn_s[k];
            float4 bnh = *(const float4*)&bhhn_s[k];
            float4 hn;
            float* pgir = (float*)&gi_r; float* pgiz = (float*)&gi_z; float* pgin = (float*)&gi_n;
            float* pghr = (float*)&ghr;  float* pghz = (float*)&ghz;  float* pghn = (float*)&ghn;
            float* pbr = (float*)&br4;   float* pbz = (float*)&bz4;
            float* pbi = (float*)&bni;   float* pbh = (float*)&bnh;
            float* ph  = (float*)&hq;    float* phn = (float*)&hn;
            #pragma unroll
            for (int e = 0; e < 4; ++e) {
                float r = 1.f / (1.f + __expf(-(pgir[e] + pghr[e] + pbr[e])));
                float z = 1.f / (1.f + __expf(-(pgiz[e] + pghz[e] + pbz[e])));
                float xx = pgin[e] + pbi[e] + r * (pghn[e] + pbh[e]);
                float e2 = __expf(2.f * xx);
                float n = 1.f - 2.f / (e2 + 1.f);
                phn[e] = (1.f - z) * n + z * ph[e];
            }
            hq = hn;
            unsigned int u01 = (unsigned int)f2bf(hn.x) | ((unsigned int)f2bf(hn.y) << 16);
            unsigned int u23 = (unsigned int)f2bf(hn.z) | ((unsigned int)f2bf(hn.w) << 16);
            *(uint2*)&hbf[hbf_idx(b, k)] = (uint2){u01, u23};
        }
        __syncthreads();   // bar2: hbf ready for next step
    }

    if (vB) *(float4*)(out + bB * HH + cB * 4) = hq;
}

extern "C" void kernel_launch(void* const* d_in, const int* in_sizes, int n_in,
                              void* d_out, int out_size, void* d_ws, size_t ws_size,
                              hipStream_t stream) {
    (void)in_sizes; (void)n_in; (void)out_size; (void)ws_size;
    const float* x    = (const float*)d_in[0];
    const float* guid = (const float*)d_in[1];
    const float* wx   = (const float*)d_in[2];
    const float* Wh   = (const float*)d_in[3];
    const float* bh   = (const float*)d_in[4];
    const float* W_ih = (const float*)d_in[5];
    const float* W_hh = (const float*)d_in[6];
    const float* b_ih = (const float*)d_in[7];
    const float* b_hh = (const float*)d_in[8];
    const float* h0   = (const float*)d_in[9];
    float* ws  = (float*)d_ws;
    float* out = (float*)d_out;

    hipLaunchKernelGGL(prep_kernel, dim3(63), dim3(256), 0, stream,
                       x, wx, W_ih, W_hh, Wh, ws);
    hipLaunchKernelGGL(recurrence_kernel, dim3(1), dim3(512), 0, stream,
                       guid, bh, b_ih, b_hh, h0, ws, out);
}